// Round 1
// baseline (17066.614 us; speedup 1.0000x reference)
//
#include <hip/hip_runtime.h>
#include <hip/hip_bf16.h>

// SNN: 5 layers (4 hidden Leaky + output Leaky), T=100 steps, B=512.
// Per (t, layer): fused GEMM (C = X @ W^T + b) + Leaky membrane update.
// fp32 everywhere (reference is fp32; no fp32 MFMA on CDNA4 -> vector FMA).

#define NB 512        // batch
#define NH 1024       // hidden
#define NI 512        // inputs
#define NO 35         // outputs
#define TT 100        // timesteps

// GEMM tile: BM=32 (batch rows), BN=64 (neurons), BK=32.
// 256 threads: tx = tid&15 -> 4 neurons each, ty = tid>>4 -> 2 rows each.
#define BM 32
#define BN 64
#define BK 32

__device__ inline void leaky_upd(float zin, float mprev, float be, float th,
                                 float& mnew, float& spk) {
    float rs = (mprev - th > 0.0f) ? th : 0.0f;          // reset*thr (detached)
    float bc = fminf(fmaxf(be, 0.0f), 1.0f);             // clip(beta,0,1)
    mnew = bc * mprev + zin - rs;
    spk  = (mnew - th > 0.0f) ? 1.0f : 0.0f;
}

// C[b][n] = sum_k X[b][k] * W[n][k] + bias[n]; then Leaky update on mem[b][n],
// spikes written to spk_out[b][n].
__global__ __launch_bounds__(256)
void gemm_leaky(const float* __restrict__ X,     // [B][K]
                const float* __restrict__ W,     // [N][K]
                const float* __restrict__ bias,  // [N]
                float* __restrict__ mem,         // [B][N]
                const float* __restrict__ beta,  // [N]
                const float* __restrict__ thr,   // [N]
                float* __restrict__ spk_out,     // [B][N]
                int N, int K)
{
    // transposed tiles: [k][b] and [k][n]; pads keep 8B/16B alignment of rows.
    __shared__ float Xs[BK][BM + 2];   // row = 34 floats = 136B (8B aligned)
    __shared__ float Ws[BK][BN + 4];   // row = 68 floats = 272B (16B aligned)

    const int tid = threadIdx.x;
    const int tx  = tid & 15;          // neuron group (4 each)
    const int ty  = tid >> 4;          // batch group (2 each)
    const int n0  = blockIdx.x * BN;
    const int b0  = blockIdx.y * BM;

    float acc[2][4] = {{0.f,0.f,0.f,0.f},{0.f,0.f,0.f,0.f}};

    const int lr = tid >> 3;           // 0..31
    const int lc = (tid & 7) * 4;      // 0,4,...,28

    for (int kk = 0; kk < K; kk += BK) {
        // stage X tile (32b x 32k), transposed into Xs[k][b]
        {
            float4 v = *reinterpret_cast<const float4*>(&X[(size_t)(b0 + lr) * K + kk + lc]);
            Xs[lc + 0][lr] = v.x;
            Xs[lc + 1][lr] = v.y;
            Xs[lc + 2][lr] = v.z;
            Xs[lc + 3][lr] = v.w;
        }
        // stage W tile (64n x 32k), transposed into Ws[k][n]
        #pragma unroll
        for (int h = 0; h < 2; ++h) {
            int n = lr + h * 32;
            float4 v = *reinterpret_cast<const float4*>(&W[(size_t)(n0 + n) * K + kk + lc]);
            Ws[lc + 0][n] = v.x;
            Ws[lc + 1][n] = v.y;
            Ws[lc + 2][n] = v.z;
            Ws[lc + 3][n] = v.w;
        }
        __syncthreads();

        #pragma unroll
        for (int k = 0; k < BK; ++k) {
            float2 xv = *reinterpret_cast<const float2*>(&Xs[k][ty * 2]);
            float4 wv = *reinterpret_cast<const float4*>(&Ws[k][tx * 4]);
            acc[0][0] += xv.x * wv.x;
            acc[0][1] += xv.x * wv.y;
            acc[0][2] += xv.x * wv.z;
            acc[0][3] += xv.x * wv.w;
            acc[1][0] += xv.y * wv.x;
            acc[1][1] += xv.y * wv.y;
            acc[1][2] += xv.y * wv.z;
            acc[1][3] += xv.y * wv.w;
        }
        __syncthreads();
    }

    const int nidx = n0 + tx * 4;
    float4 bev = *reinterpret_cast<const float4*>(&beta[nidx]);
    float4 thv = *reinterpret_cast<const float4*>(&thr[nidx]);
    float4 biv = *reinterpret_cast<const float4*>(&bias[nidx]);

    #pragma unroll
    for (int i = 0; i < 2; ++i) {
        const int bidx = b0 + ty * 2 + i;
        float4 mv = *reinterpret_cast<const float4*>(&mem[(size_t)bidx * N + nidx]);
        float4 mo, so;
        leaky_upd(acc[i][0] + biv.x, mv.x, bev.x, thv.x, mo.x, so.x);
        leaky_upd(acc[i][1] + biv.y, mv.y, bev.y, thv.y, mo.y, so.y);
        leaky_upd(acc[i][2] + biv.z, mv.z, bev.z, thv.z, mo.z, so.z);
        leaky_upd(acc[i][3] + biv.w, mv.w, bev.w, thv.w, mo.w, so.w);
        *reinterpret_cast<float4*>(&mem[(size_t)bidx * N + nidx])     = mo;
        *reinterpret_cast<float4*>(&spk_out[(size_t)bidx * N + nidx]) = so;
    }
}

// Output layer: z[b][o] = spk[b][:] . W_out[o][:] + b_out[o]; Leaky; write spikes.
__global__ __launch_bounds__(64)
void out_leaky(const float* __restrict__ X,     // [B][NH] spikes
               const float* __restrict__ W,     // [NO][NH]
               const float* __restrict__ bias,  // [NO]
               float* __restrict__ mem,         // [B][NO]
               const float* __restrict__ beta,  // [NO]
               const float* __restrict__ thr,   // [NO]
               float* __restrict__ out)         // [B][NO] slice of d_out
{
    const int b = blockIdx.x;
    const int o = threadIdx.x;
    if (o >= NO) return;

    const float* xr = X + (size_t)b * NH;
    const float* wr = W + (size_t)o * NH;
    float acc = 0.0f;
    #pragma unroll 4
    for (int k = 0; k < NH; k += 4) {
        float4 xv = *reinterpret_cast<const float4*>(&xr[k]);
        float4 wv = *reinterpret_cast<const float4*>(&wr[k]);
        acc += xv.x * wv.x + xv.y * wv.y + xv.z * wv.z + xv.w * wv.w;
    }
    acc += bias[o];

    float mp = mem[b * NO + o];
    float mn, sp;
    leaky_upd(acc, mp, beta[o], thr[o], mn, sp);
    mem[b * NO + o] = mn;
    out[b * NO + o] = sp;
}

extern "C" void kernel_launch(void* const* d_in, const int* in_sizes, int n_in,
                              void* d_out, int out_size, void* d_ws, size_t ws_size,
                              hipStream_t stream) {
    const float* data   = (const float*)d_in[0];   // [T][B][NI]
    const float* W_in   = (const float*)d_in[1];   // [NH][NI]
    const float* b_in   = (const float*)d_in[2];   // [NH]
    const float* W_h    = (const float*)d_in[3];   // [3][NH][NH]
    const float* b_h    = (const float*)d_in[4];   // [3][NH]
    const float* W_out  = (const float*)d_in[5];   // [NO][NH]
    const float* b_out  = (const float*)d_in[6];   // [NO]
    const float* beta_h = (const float*)d_in[7];   // [4][NH]
    const float* thr_h  = (const float*)d_in[8];   // [4][NH]
    const float* beta_o = (const float*)d_in[9];   // [NO]
    const float* thr_o  = (const float*)d_in[10];  // [NO]
    float* out = (float*)d_out;                    // [T][B][NO]

    float* ws    = (float*)d_ws;
    float* mem_h = ws;                                   // 4 * B * NH
    float* mem_o = mem_h + 4 * NB * NH;                  // B * NO
    float* spk_a = mem_o + NB * NO;                      // B * NH
    float* spk_b = spk_a + NB * NH;                      // B * NH

    // zero membranes each call (deterministic under graph replay)
    hipMemsetAsync(ws, 0, (size_t)(4 * NB * NH + NB * NO) * sizeof(float), stream);

    dim3 blk(256);
    dim3 grd(NH / BN, NB / BM);   // 16 x 16 = 256 blocks

    for (int t = 0; t < TT; ++t) {
        const float* xt = data + (size_t)t * NB * NI;
        // layer 0: input GEMM (K=NI)
        gemm_leaky<<<grd, blk, 0, stream>>>(xt, W_in, b_in,
                                            mem_h + 0 * NB * NH,
                                            beta_h + 0 * NH, thr_h + 0 * NH,
                                            spk_a, NH, NI);
        // hidden layers 1..3 (K=NH)
        gemm_leaky<<<grd, blk, 0, stream>>>(spk_a, W_h + 0 * NH * NH, b_h + 0 * NH,
                                            mem_h + 1 * NB * NH,
                                            beta_h + 1 * NH, thr_h + 1 * NH,
                                            spk_b, NH, NH);
        gemm_leaky<<<grd, blk, 0, stream>>>(spk_b, W_h + 1 * NH * NH, b_h + 1 * NH,
                                            mem_h + 2 * NB * NH,
                                            beta_h + 2 * NH, thr_h + 2 * NH,
                                            spk_a, NH, NH);
        gemm_leaky<<<grd, blk, 0, stream>>>(spk_a, W_h + 2 * NH * NH, b_h + 2 * NH,
                                            mem_h + 3 * NB * NH,
                                            beta_h + 3 * NH, thr_h + 3 * NH,
                                            spk_b, NH, NH);
        // output layer
        out_leaky<<<dim3(NB), dim3(64), 0, stream>>>(spk_b, W_out, b_out,
                                                     mem_o, beta_o, thr_o,
                                                     out + (size_t)t * NB * NO);
    }
}

// Round 2
// 14551.181 us; speedup vs baseline: 1.1729x; 1.1729x over previous
//
#include <hip/hip_runtime.h>
#include <hip/hip_bf16.h>

// SNN: 5 layers, T=100. Layers 1-3 (binary-spike inputs) use bf16 MFMA with
// 3-way weight split (w = w1+w2+w3 bf16 planes, residual <= 2^-27|w| -> below
// fp32 noise). Layer 0 (fp32 data input) and output layer stay fp32 vector.
// Weights pre-swizzled into MFMA B-fragment tiling; spikes written by each
// producer in MFMA A-fragment tiling -> MFMA kernels need NO LDS, no barriers.

#define NB 512
#define NH 1024
#define NI 512
#define NO 35
#define TT 100

typedef __bf16 bf16x8 __attribute__((ext_vector_type(8)));
typedef float f32x4 __attribute__((ext_vector_type(4)));

// Fragment tiling for mfma_f32_16x16x32_bf16 operands over a [rows][K=1024]
// matrix: [row/16][k/32][lane][8] with lane = (row&15) | (((k>>3)&3)<<4),
// elem j = k&7.  (A: row=batch; B: row=neuron, since B[k][n] = W[n][k].)
__device__ __forceinline__ size_t tiled_off(int row, int k) {
    return ((size_t)((row >> 4) * 32 + (k >> 5)) * 64
            + (row & 15) + (((k >> 3) & 3) << 4)) * 8 + (k & 7);
}

__device__ __forceinline__ void leaky_upd(float zin, float mprev, float be, float th,
                                          float& mnew, float& spk) {
    float rs = (mprev - th > 0.0f) ? th : 0.0f;          // reset*thr (detached)
    float bc = fminf(fmaxf(be, 0.0f), 1.0f);             // clip(beta,0,1)
    mnew = bc * mprev + zin - rs;
    spk  = (mnew - th > 0.0f) ? 1.0f : 0.0f;
}

// ---------------- weight split: W_h[3][NH][NH] fp32 -> 3 bf16 planes, tiled --
__global__ __launch_bounds__(256)
void split_weights(const float* __restrict__ W_h, __bf16* __restrict__ Wt) {
    const int id = blockIdx.x * 256 + threadIdx.x;   // 3 * 1024 * 128
    const int layer = id >> 17;
    const int rem = id & 131071;
    const int n = rem >> 7;
    const int k0 = (rem & 127) << 3;
    const float* src = W_h + ((size_t)layer * NH + n) * NH + k0;
    __bf16* dst = Wt + (size_t)layer * 3 * NH * NH;
    const size_t PS = (size_t)NH * NH;
    const size_t off = tiled_off(n, k0);
    bf16x8 p1, p2, p3;
    #pragma unroll
    for (int j = 0; j < 8; ++j) {
        float w = src[j];
        __bf16 a = (__bf16)w;  float r1 = w - (float)a;
        __bf16 b = (__bf16)r1; float r2 = r1 - (float)b;
        __bf16 c = (__bf16)r2;
        p1[j] = a; p2[j] = b; p3[j] = c;
    }
    *reinterpret_cast<bf16x8*>(dst + 0 * PS + off) = p1;
    *reinterpret_cast<bf16x8*>(dst + 1 * PS + off) = p2;
    *reinterpret_cast<bf16x8*>(dst + 2 * PS + off) = p3;
}

// ---------------- layer 0: fp32 GEMM (K=NI) + leaky, spikes out in A-tiling --
#define BM 32
#define BN 64
#define BK 32

__global__ __launch_bounds__(256)
void gemm_leaky0(const float* __restrict__ X,     // [NB][NI]
                 const float* __restrict__ W,     // [NH][NI]
                 const float* __restrict__ bias,
                 float* __restrict__ mem,         // [NB][NH]
                 const float* __restrict__ beta,
                 const float* __restrict__ thr,
                 __bf16* __restrict__ spk_t)      // tiled spikes
{
    __shared__ float Xs[BK][BM + 2];
    __shared__ float Ws[BK][BN + 4];

    const int tid = threadIdx.x;
    const int tx  = tid & 15;
    const int ty  = tid >> 4;
    const int n0  = blockIdx.x * BN;
    const int b0  = blockIdx.y * BM;

    float acc[2][4] = {{0.f,0.f,0.f,0.f},{0.f,0.f,0.f,0.f}};

    const int lr = tid >> 3;
    const int lc = (tid & 7) * 4;

    for (int kk = 0; kk < NI; kk += BK) {
        {
            float4 v = *reinterpret_cast<const float4*>(&X[(size_t)(b0 + lr) * NI + kk + lc]);
            Xs[lc + 0][lr] = v.x; Xs[lc + 1][lr] = v.y;
            Xs[lc + 2][lr] = v.z; Xs[lc + 3][lr] = v.w;
        }
        #pragma unroll
        for (int h = 0; h < 2; ++h) {
            int n = lr + h * 32;
            float4 v = *reinterpret_cast<const float4*>(&W[(size_t)(n0 + n) * NI + kk + lc]);
            Ws[lc + 0][n] = v.x; Ws[lc + 1][n] = v.y;
            Ws[lc + 2][n] = v.z; Ws[lc + 3][n] = v.w;
        }
        __syncthreads();

        #pragma unroll
        for (int k = 0; k < BK; ++k) {
            float2 xv = *reinterpret_cast<const float2*>(&Xs[k][ty * 2]);
            float4 wv = *reinterpret_cast<const float4*>(&Ws[k][tx * 4]);
            acc[0][0] += xv.x * wv.x; acc[0][1] += xv.x * wv.y;
            acc[0][2] += xv.x * wv.z; acc[0][3] += xv.x * wv.w;
            acc[1][0] += xv.y * wv.x; acc[1][1] += xv.y * wv.y;
            acc[1][2] += xv.y * wv.z; acc[1][3] += xv.y * wv.w;
        }
        __syncthreads();
    }

    const int nidx = n0 + tx * 4;
    float4 bev = *reinterpret_cast<const float4*>(&beta[nidx]);
    float4 thv = *reinterpret_cast<const float4*>(&thr[nidx]);
    float4 biv = *reinterpret_cast<const float4*>(&bias[nidx]);

    #pragma unroll
    for (int i = 0; i < 2; ++i) {
        const int bidx = b0 + ty * 2 + i;
        float4 mv = *reinterpret_cast<const float4*>(&mem[(size_t)bidx * NH + nidx]);
        float4 mo; float s0, s1, s2, s3;
        leaky_upd(acc[i][0] + biv.x, mv.x, bev.x, thv.x, mo.x, s0);
        leaky_upd(acc[i][1] + biv.y, mv.y, bev.y, thv.y, mo.y, s1);
        leaky_upd(acc[i][2] + biv.z, mv.z, bev.z, thv.z, mo.z, s2);
        leaky_upd(acc[i][3] + biv.w, mv.w, bev.w, thv.w, mo.w, s3);
        *reinterpret_cast<float4*>(&mem[(size_t)bidx * NH + nidx]) = mo;
        spk_t[tiled_off(bidx, nidx + 0)] = (__bf16)s0;
        spk_t[tiled_off(bidx, nidx + 1)] = (__bf16)s1;
        spk_t[tiled_off(bidx, nidx + 2)] = (__bf16)s2;
        spk_t[tiled_off(bidx, nidx + 3)] = (__bf16)s3;
    }
}

// ---------------- hidden layers 1-3: bf16 MFMA GEMM + leaky -----------------
// grid (16, 8): block tile 64B x 64N, 4 waves (2x2), wave tile 32x32.
__global__ __launch_bounds__(256)
void gemm_leaky_mfma(const __bf16* __restrict__ Xt,   // tiled spikes in
                     const __bf16* __restrict__ Wt,   // 3 tiled planes (layer)
                     const float* __restrict__ bias,
                     float* __restrict__ mem,         // [NB][NH]
                     const float* __restrict__ beta,
                     const float* __restrict__ thr,
                     __bf16* __restrict__ Yt)         // tiled spikes out
{
    const int lane = threadIdx.x & 63;
    const int w    = threadIdx.x >> 6;
    const int wm   = w >> 1, wn = w & 1;
    const int b0   = blockIdx.y * 64 + wm * 32;
    const int n0   = blockIdx.x * 64 + wn * 32;
    const int mt0  = b0 >> 4;
    const int nt0  = n0 >> 4;
    const size_t PS = (size_t)NH * NH;

    f32x4 acc[2][2] = {};

    for (int kt = 0; kt < 32; ++kt) {
        bf16x8 a0 = *reinterpret_cast<const bf16x8*>(Xt + ((size_t)((mt0 + 0) * 32 + kt) * 64 + lane) * 8);
        bf16x8 a1 = *reinterpret_cast<const bf16x8*>(Xt + ((size_t)((mt0 + 1) * 32 + kt) * 64 + lane) * 8);
        #pragma unroll
        for (int p = 0; p < 3; ++p) {
            bf16x8 q0 = *reinterpret_cast<const bf16x8*>(Wt + p * PS + ((size_t)((nt0 + 0) * 32 + kt) * 64 + lane) * 8);
            bf16x8 q1 = *reinterpret_cast<const bf16x8*>(Wt + p * PS + ((size_t)((nt0 + 1) * 32 + kt) * 64 + lane) * 8);
            acc[0][0] = __builtin_amdgcn_mfma_f32_16x16x32_bf16(a0, q0, acc[0][0], 0, 0, 0);
            acc[0][1] = __builtin_amdgcn_mfma_f32_16x16x32_bf16(a0, q1, acc[0][1], 0, 0, 0);
            acc[1][0] = __builtin_amdgcn_mfma_f32_16x16x32_bf16(a1, q0, acc[1][0], 0, 0, 0);
            acc[1][1] = __builtin_amdgcn_mfma_f32_16x16x32_bf16(a1, q1, acc[1][1], 0, 0, 0);
        }
    }

    // epilogue: D lane mapping col = lane&15, row = (lane>>4)*4 + r
    const int r0 = (lane >> 4) * 4;
    const int c  = lane & 15;
    #pragma unroll
    for (int ni = 0; ni < 2; ++ni) {
        const int n = n0 + ni * 16 + c;
        const float bi = bias[n], be = beta[n], th = thr[n];
        #pragma unroll
        for (int mi = 0; mi < 2; ++mi) {
            #pragma unroll
            for (int r = 0; r < 4; ++r) {
                const int b = b0 + mi * 16 + r0 + r;
                float z = acc[mi][ni][r] + bi;
                float mp = mem[(size_t)b * NH + n];
                float mn, sp;
                leaky_upd(z, mp, be, th, mn, sp);
                mem[(size_t)b * NH + n] = mn;
                Yt[tiled_off(b, n)] = (__bf16)sp;
            }
        }
    }
}

// ---------------- output layer: fp32 dot over tiled bf16 spikes -------------
__global__ __launch_bounds__(64)
void out_leaky_k(const __bf16* __restrict__ Xt,   // tiled spikes
                 const float* __restrict__ W,     // [NO][NH]
                 const float* __restrict__ bias,
                 float* __restrict__ mem,         // [NB][NO]
                 const float* __restrict__ beta,
                 const float* __restrict__ thr,
                 float* __restrict__ out)         // [NB][NO]
{
    const int b = blockIdx.x;
    const int o = threadIdx.x;
    if (o >= NO) return;

    const float* wr = W + (size_t)o * NH;
    float acc = 0.0f;
    for (int k0 = 0; k0 < NH; k0 += 8) {
        bf16x8 xv = *reinterpret_cast<const bf16x8*>(Xt + tiled_off(b, k0));
        float4 w0 = *reinterpret_cast<const float4*>(wr + k0);
        float4 w1 = *reinterpret_cast<const float4*>(wr + k0 + 4);
        acc += (float)xv[0] * w0.x + (float)xv[1] * w0.y
             + (float)xv[2] * w0.z + (float)xv[3] * w0.w
             + (float)xv[4] * w1.x + (float)xv[5] * w1.y
             + (float)xv[6] * w1.z + (float)xv[7] * w1.w;
    }
    acc += bias[o];

    float mp = mem[b * NO + o];
    float mn, sp;
    leaky_upd(acc, mp, beta[o], thr[o], mn, sp);
    mem[b * NO + o] = mn;
    out[b * NO + o] = sp;
}

extern "C" void kernel_launch(void* const* d_in, const int* in_sizes, int n_in,
                              void* d_out, int out_size, void* d_ws, size_t ws_size,
                              hipStream_t stream) {
    const float* data   = (const float*)d_in[0];
    const float* W_in   = (const float*)d_in[1];
    const float* b_in   = (const float*)d_in[2];
    const float* W_h    = (const float*)d_in[3];
    const float* b_h    = (const float*)d_in[4];
    const float* W_out  = (const float*)d_in[5];
    const float* b_out  = (const float*)d_in[6];
    const float* beta_h = (const float*)d_in[7];
    const float* thr_h  = (const float*)d_in[8];
    const float* beta_o = (const float*)d_in[9];
    const float* thr_o  = (const float*)d_in[10];
    float* out = (float*)d_out;

    char* ws = (char*)d_ws;
    float* mem_h = (float*)ws;                              // 4*NB*NH fp32
    float* mem_o = mem_h + 4 * NB * NH;                     // NB*NO fp32
    __bf16* spkA = (__bf16*)(ws + 8460288);                 // NB*NH bf16 (tiled)
    __bf16* spkB = spkA + (size_t)NB * NH;
    __bf16* Wt   = spkB + (size_t)NB * NH;                  // 3 layers * 3 planes * NH*NH
    const size_t PS3 = (size_t)3 * NH * NH;                 // per-layer plane group

    hipMemsetAsync(mem_h, 0, (size_t)(4 * NB * NH + NB * NO) * sizeof(float), stream);
    split_weights<<<dim3(1536), dim3(256), 0, stream>>>(W_h, Wt);

    dim3 blk(256);
    dim3 grd0(NH / BN, NB / BM);   // 16 x 16
    dim3 grdh(16, 8);              // hidden MFMA

    for (int t = 0; t < TT; ++t) {
        const float* xt = data + (size_t)t * NB * NI;
        gemm_leaky0<<<grd0, blk, 0, stream>>>(xt, W_in, b_in,
                                              mem_h + 0 * (size_t)NB * NH,
                                              beta_h + 0 * NH, thr_h + 0 * NH, spkA);
        gemm_leaky_mfma<<<grdh, blk, 0, stream>>>(spkA, Wt + 0 * PS3, b_h + 0 * NH,
                                                  mem_h + 1 * (size_t)NB * NH,
                                                  beta_h + 1 * NH, thr_h + 1 * NH, spkB);
        gemm_leaky_mfma<<<grdh, blk, 0, stream>>>(spkB, Wt + 1 * PS3, b_h + 1 * NH,
                                                  mem_h + 2 * (size_t)NB * NH,
                                                  beta_h + 2 * NH, thr_h + 2 * NH, spkA);
        gemm_leaky_mfma<<<grdh, blk, 0, stream>>>(spkA, Wt + 2 * PS3, b_h + 2 * NH,
                                                  mem_h + 3 * (size_t)NB * NH,
                                                  beta_h + 3 * NH, thr_h + 3 * NH, spkB);
        out_leaky_k<<<dim3(NB), dim3(64), 0, stream>>>(spkB, W_out, b_out,
                                                       mem_o, beta_o, thr_o,
                                                       out + (size_t)t * NB * NO);
    }
}